// Round 5
// baseline (755.110 us; speedup 1.0000x reference)
//
#include <hip/hip_runtime.h>

#define E_TOT   400000
#define N_NODES 50000
#define H_DIM   128
#define D_DIM   256
#define TE      128                 // edges per block
#define NBLK    (E_TOT / TE)        // 3125 tower blocks
#define NB_TOT  3910                // 3125 tower + 782 gather + 3 idle, interleaved
#define NSCAN_BLK 196               // ceil(50000/256)

typedef _Float16 f16x4 __attribute__((ext_vector_type(4)));
typedef _Float16 f16x8 __attribute__((ext_vector_type(8)));
typedef float    f32x2 __attribute__((ext_vector_type(2)));
typedef float    f32x4 __attribute__((ext_vector_type(4)));
typedef float    f32x16 __attribute__((ext_vector_type(16)));

// swizzled f16 index into the [128][256] LDS tile: XOR row bits into the
// 16B-chunk bits of the column so stride-512B column reads spread across banks
__device__ __forceinline__ int swz(int row, int col) {
    return row * 256 + (col ^ ((row & 7) << 3));
}

__device__ __forceinline__ f32x16 zero16() {
    f32x16 z = {0.f,0.f,0.f,0.f,0.f,0.f,0.f,0.f,0.f,0.f,0.f,0.f,0.f,0.f,0.f,0.f};
    return z;
}

// ---------------------------------------------------------------------------
// Prep: repack w_up [128][256] and Ws [3][256][256] (fp32, [in][out]) into
// fragment-ordered f16: elem(lane,j) = W[kb*16 + 8*(lane>>5)+j][nb*32+(lane&31)]
// ---------------------------------------------------------------------------
__global__ void prep_weights(const float* __restrict__ w_up,
                             const float* __restrict__ Ws,
                             _Float16* __restrict__ wf)
{
    int t = blockIdx.x * 256 + threadIdx.x;    // 0 .. 229375
    int j    = t & 7;
    int lane = (t >> 3) & 63;
    int frag = t >> 9;
    int khalf = (lane >> 5) << 3;
    int col31 = lane & 31;
    float v;
    if (frag < 64) {                           // w_up: K=128 -> kb 0..7
        int nb = frag >> 3, kb = frag & 7;
        v = w_up[(kb * 16 + khalf + j) * 256 + nb * 32 + col31];
    } else {                                   // Ws: K=256 -> kb 0..15
        int f2 = frag - 64;
        int layer = f2 >> 7;
        int fl = f2 & 127;
        int nb = fl >> 4, kb = fl & 15;
        v = Ws[layer * 65536 + (kb * 16 + khalf + j) * 256 + nb * 32 + col31];
    }
    wf[t] = (_Float16)v;
}

// ---------------------------------------------------------------------------
// CSR build: histogram -> 2-level exclusive scan -> scatter edge ids
// ---------------------------------------------------------------------------
__global__ void k_hist(const int* __restrict__ ni, int* __restrict__ counts) {
    int e = blockIdx.x * 256 + threadIdx.x;
    if (e < E_TOT) atomicAdd(&counts[ni[e]], 1);
}

__global__ void k_scan_block(const int* __restrict__ counts,
                             int* __restrict__ starts, int* __restrict__ bsum) {
    __shared__ int s[256];
    int tid = threadIdx.x;
    int idx = blockIdx.x * 256 + tid;
    int v = (idx < N_NODES) ? counts[idx] : 0;
    s[tid] = v; __syncthreads();
    #pragma unroll
    for (int off = 1; off < 256; off <<= 1) {
        int t = (tid >= off) ? s[tid - off] : 0; __syncthreads();
        s[tid] += t; __syncthreads();
    }
    if (idx < N_NODES) starts[idx] = s[tid] - v;       // local exclusive
    if (tid == 255) bsum[blockIdx.x] = s[255];         // block total
}

__global__ void k_scan_top(int* __restrict__ bsum) {
    __shared__ int s[256];
    int tid = threadIdx.x;
    int v = (tid < NSCAN_BLK) ? bsum[tid] : 0;
    s[tid] = v; __syncthreads();
    #pragma unroll
    for (int off = 1; off < 256; off <<= 1) {
        int t = (tid >= off) ? s[tid - off] : 0; __syncthreads();
        s[tid] += t; __syncthreads();
    }
    if (tid < NSCAN_BLK) bsum[tid] = s[tid] - v;       // exclusive
}

__global__ void k_scan_add(int* __restrict__ starts, const int* __restrict__ bsum,
                           int* __restrict__ cursor) {
    int idx = blockIdx.x * 256 + threadIdx.x;
    if (idx < N_NODES) {
        int v = starts[idx] + bsum[blockIdx.x];
        starts[idx] = v;
        cursor[idx] = v;
    }
    if (idx == 0) starts[N_NODES] = E_TOT;
}

__global__ void k_scatter(const int* __restrict__ ni, int* __restrict__ cursor,
                          int* __restrict__ eid) {
    int e = blockIdx.x * 256 + threadIdx.x;
    if (e < E_TOT) {
        int slot = atomicAdd(&cursor[ni[e]], 1);
        eid[slot] = e;
    }
}

// ---------------------------------------------------------------------------
// Merged kernel: blocks with bid%5==4 do the node-gather (x_spe); the rest run
// the edge tower. Gather latency hides under tower MFMA on co-resident blocks.
// ---------------------------------------------------------------------------
__global__ __launch_bounds__(512, 4)
void fused_main(const float* __restrict__ x,
                const float* __restrict__ rbf,
                const float* __restrict__ w_rbf,
                const float* __restrict__ bs,
                const float* __restrict__ w_out,
                const _Float16* __restrict__ wf,
                const int* __restrict__ starts,
                const int* __restrict__ eid,
                float* __restrict__ xspe,
                float* __restrict__ out)
{
    __shared__ __align__(16) _Float16 tbuf[TE * 256];   // 64 KB
    const int tid = threadIdx.x;
    const int bid = blockIdx.x;

    // ================= gather role =================
    if ((bid % 5) == 4) {
        int gbid = bid / 5;                 // 0..781
        int w    = tid >> 6;
        int l    = tid & 63;
        int node = gbid * 8 + w;            // up to 6255
        if (node >= N_NODES / 8) { }        // (node covers 0..6255 wave-slots)
        node = gbid * 8 + w;
        if (node < 6256) {
            int nd = node * 8;              // each wave handles 8 nodes? no:
        }
        // one wave per node, lanes cover 2 cols each
        int n0 = gbid * 8 + w;
        if (n0 < 50000 / 8 + 1) { }
        // (simple form below)
        int nodeid = gbid * 8 + w;
        if (nodeid * 8 >= 0) { }
        {
            int nn = gbid * 8 + w;
            if (nn < 6250 * 8) { }
        }
        int node_i = gbid * 8 + w;          // need 6250 waves for 50000 nodes? no:
        // 50000 nodes / (782 blocks * 8 waves) -> each wave does 8 nodes
        int c0 = l * 2;
        float wr[6][2];
        #pragma unroll
        for (int r = 0; r < 6; ++r) {
            wr[r][0] = w_rbf[r * 128 + c0];
            wr[r][1] = w_rbf[r * 128 + c0 + 1];
        }
        #pragma unroll
        for (int rep = 0; rep < 8; ++rep) {
            int nd = (gbid * 8 + w) * 8 + rep;   // 8 nodes per wave
            if (nd >= N_NODES) break;
            int kb = starts[nd], ke = starts[nd + 1];
            float a0 = 0.f, a1 = 0.f;
            for (int k = kb; k < ke; ++k) {
                int e = eid[k];
                float rb[6];
                #pragma unroll
                for (int r = 0; r < 6; ++r) rb[r] = rbf[(size_t)e * 6 + r];
                f32x2 xv = *(const f32x2*)(x + (size_t)e * 128 + c0);
                float s0 = 0.f, s1 = 0.f;
                #pragma unroll
                for (int r = 0; r < 6; ++r) { s0 += rb[r] * wr[r][0]; s1 += rb[r] * wr[r][1]; }
                a0 += s0 * xv[0];
                a1 += s1 * xv[1];
            }
            f32x2 o = {a0, a1};
            *(f32x2*)(xspe + (size_t)nd * 128 + c0) = o;
        }
        return;
    }

    // ================= tower role =================
    const int tbid = bid - bid / 5;
    if (tbid >= NBLK) return;
    const int e0 = tbid * TE;

    // ---------------- stage 1: h tile (f16), 4 cols x 8 edges per thread ----
    {
        const int cg = tid & 31;        // 32 col groups of 4
        const int eg = tid >> 5;        // 16 edge groups of 8
        const int c0 = cg << 2;
        float wr[6][4];
        #pragma unroll
        for (int r = 0; r < 6; ++r)
            #pragma unroll
            for (int c = 0; c < 4; ++c)
                wr[r][c] = w_rbf[r * 128 + c0 + c];

        #pragma unroll
        for (int ee = 0; ee < 8; ++ee) {
            int el = eg * 8 + ee;
            int e  = e0 + el;
            float rb[6];
            #pragma unroll
            for (int r = 0; r < 6; ++r) rb[r] = rbf[(size_t)e * 6 + r];
            f32x4 xv = *(const f32x4*)(x + (size_t)e * 128 + c0);
            f16x4 hv;
            #pragma unroll
            for (int c = 0; c < 4; ++c) {
                float s = 0.f;
                #pragma unroll
                for (int r = 0; r < 6; ++r) s += rb[r] * wr[r][c];
                hv[c] = (_Float16)(s * xv[c]);
            }
            *(f16x4*)&tbuf[swz(el, c0)] = hv;   // 4-col chunk, swz preserves bit2
        }
    }
    __syncthreads();

    const int l    = tid & 63;
    const int w    = tid >> 6;          // 0..7
    const int rs   = w >> 2;            // row half 0/1
    const int cs   = w & 3;             // col quarter 0..3
    const int l31  = l & 31;
    const int lh   = l >> 5;
    const int khalf = lh << 3;
    const int r0   = rs * 64;

    const f16x8* __restrict__ wupf = (const f16x8*)wf;
    const f16x8* __restrict__ wlf  = ((const f16x8*)wf) + 4096;

    f32x16 acc00, acc01, acc10, acc11;

    // ---------------- GEMM1: t1 = h @ w_up (K=128) ----------------
    acc00 = acc01 = acc10 = acc11 = zero16();
    {
        f16x8 bc0 = wupf[((cs * 2 + 0) * 8 + 0) * 64 + l];
        f16x8 bc1 = wupf[((cs * 2 + 1) * 8 + 0) * 64 + l];
        #pragma unroll
        for (int kb = 0; kb < 8; ++kb) {
            f16x8 bn0, bn1;
            if (kb < 7) {
                bn0 = wupf[((cs * 2 + 0) * 8 + kb + 1) * 64 + l];
                bn1 = wupf[((cs * 2 + 1) * 8 + kb + 1) * 64 + l];
            }
            int k0 = kb * 16 + khalf;
            f16x8 a0 = *(const f16x8*)&tbuf[swz(r0 +  0 + l31, k0)];
            f16x8 a1 = *(const f16x8*)&tbuf[swz(r0 + 32 + l31, k0)];
            acc00 = __builtin_amdgcn_mfma_f32_32x32x16_f16(a0, bc0, acc00, 0, 0, 0);
            acc10 = __builtin_amdgcn_mfma_f32_32x32x16_f16(a1, bc0, acc10, 0, 0, 0);
            acc01 = __builtin_amdgcn_mfma_f32_32x32x16_f16(a0, bc1, acc01, 0, 0, 0);
            acc11 = __builtin_amdgcn_mfma_f32_32x32x16_f16(a1, bc1, acc11, 0, 0, 0);
            bc0 = bn0; bc1 = bn1;
        }
    }
    __syncthreads();
    {
        int cg0 = cs * 64 + l31;
        #pragma unroll
        for (int r = 0; r < 16; ++r) {
            int rowl = (r & 3) + 8 * (r >> 2) + 4 * lh;   // C/D layout m74/m101
            tbuf[swz(r0 +  0 + rowl, cg0)]      = (_Float16)acc00[r];
            tbuf[swz(r0 +  0 + rowl, cg0 + 32)] = (_Float16)acc01[r];
            tbuf[swz(r0 + 32 + rowl, cg0)]      = (_Float16)acc10[r];
            tbuf[swz(r0 + 32 + rowl, cg0 + 32)] = (_Float16)acc11[r];
        }
    }
    __syncthreads();

    // ---------------- 3x: t = silu(t @ W + b), K=256 ----------------
    for (int layer = 0; layer < 3; ++layer) {
        const f16x8* wl = wlf + layer * 8192;
        float bias0 = bs[layer * 256 + cs * 64 + l31];
        float bias1 = bs[layer * 256 + cs * 64 + 32 + l31];
        acc00 = acc01 = acc10 = acc11 = zero16();

        f16x8 bc0 = wl[((cs * 2 + 0) * 16 + 0) * 64 + l];
        f16x8 bc1 = wl[((cs * 2 + 1) * 16 + 0) * 64 + l];
        #pragma unroll
        for (int kb = 0; kb < 16; ++kb) {
            f16x8 bn0, bn1;
            if (kb < 15) {
                bn0 = wl[((cs * 2 + 0) * 16 + kb + 1) * 64 + l];
                bn1 = wl[((cs * 2 + 1) * 16 + kb + 1) * 64 + l];
            }
            int k0 = kb * 16 + khalf;
            f16x8 a0 = *(const f16x8*)&tbuf[swz(r0 +  0 + l31, k0)];
            f16x8 a1 = *(const f16x8*)&tbuf[swz(r0 + 32 + l31, k0)];
            acc00 = __builtin_amdgcn_mfma_f32_32x32x16_f16(a0, bc0, acc00, 0, 0, 0);
            acc10 = __builtin_amdgcn_mfma_f32_32x32x16_f16(a1, bc0, acc10, 0, 0, 0);
            acc01 = __builtin_amdgcn_mfma_f32_32x32x16_f16(a0, bc1, acc01, 0, 0, 0);
            acc11 = __builtin_amdgcn_mfma_f32_32x32x16_f16(a1, bc1, acc11, 0, 0, 0);
            bc0 = bn0; bc1 = bn1;
        }
        __syncthreads();
        {
            int cg0 = cs * 64 + l31;
            #pragma unroll
            for (int r = 0; r < 16; ++r) {
                int rowl = (r & 3) + 8 * (r >> 2) + 4 * lh;
                float v00 = acc00[r] + bias0;
                float v01 = acc01[r] + bias1;
                float v10 = acc10[r] + bias0;
                float v11 = acc11[r] + bias1;
                float s00 = __builtin_amdgcn_rcpf(1.0f + __expf(-v00));
                float s01 = __builtin_amdgcn_rcpf(1.0f + __expf(-v01));
                float s10 = __builtin_amdgcn_rcpf(1.0f + __expf(-v10));
                float s11 = __builtin_amdgcn_rcpf(1.0f + __expf(-v11));
                tbuf[swz(r0 +  0 + rowl, cg0)]      = (_Float16)(v00 * s00);
                tbuf[swz(r0 +  0 + rowl, cg0 + 32)] = (_Float16)(v01 * s01);
                tbuf[swz(r0 + 32 + rowl, cg0)]      = (_Float16)(v10 * s10);
                tbuf[swz(r0 + 32 + rowl, cg0 + 32)] = (_Float16)(v11 * s11);
            }
        }
        __syncthreads();
    }

    // ---------------- out = t3 @ w_out  (O=1, VALU dot) ----------------
    // chunk order rotated by q*2 so the 4 quarters hit disjoint bank groups
    {
        int el = tid >> 2;              // 0..127
        int q  = tid & 3;
        int cbase = q * 64;
        float sum = 0.f;
        #pragma unroll
        for (int ch = 0; ch < 8; ++ch) {
            int c = cbase + (((ch + q * 2) & 7) << 3);
            f16x8 tv = *(const f16x8*)&tbuf[swz(el, c)];
            #pragma unroll
            for (int jj = 0; jj < 8; ++jj)
                sum += (float)tv[jj] * w_out[c + jj];
        }
        sum += __shfl_xor(sum, 1);
        sum += __shfl_xor(sum, 2);
        if (q == 0) out[e0 + el] = sum;
    }
}

extern "C" void kernel_launch(void* const* d_in, const int* in_sizes, int n_in,
                              void* d_out, int out_size, void* d_ws, size_t ws_size,
                              hipStream_t stream)
{
    const float* x     = (const float*)d_in[0];
    const float* rbf   = (const float*)d_in[1];
    const int*   nidx  = (const int*)d_in[2];
    const float* w_rbf = (const float*)d_in[3];
    const float* w_up  = (const float*)d_in[4];
    const float* Ws    = (const float*)d_in[5];
    const float* bs    = (const float*)d_in[6];
    const float* w_out = (const float*)d_in[7];

    float* xspe = (float*)d_out;                       // [N,128]
    float* outp = xspe + (size_t)N_NODES * H_DIM;      // [E,1]

    char* ws = (char*)d_ws;
    _Float16* wf   = (_Float16*)ws;                    // 458752 B
    int* counts    = (int*)(ws + 0x080000);            // 50000
    int* starts    = (int*)(ws + 0x0C0000);            // 50001
    int* cursor    = (int*)(ws + 0x100000);            // 50000
    int* bsum      = (int*)(ws + 0x140000);            // 196
    int* eid       = (int*)(ws + 0x150000);            // 400000

    hipMemsetAsync(counts, 0, N_NODES * sizeof(int), stream);
    prep_weights<<<dim3(896), dim3(256), 0, stream>>>(w_up, Ws, wf);
    k_hist      <<<dim3(1563), dim3(256), 0, stream>>>(nidx, counts);
    k_scan_block<<<dim3(NSCAN_BLK), dim3(256), 0, stream>>>(counts, starts, bsum);
    k_scan_top  <<<dim3(1), dim3(256), 0, stream>>>(bsum);
    k_scan_add  <<<dim3(NSCAN_BLK), dim3(256), 0, stream>>>(starts, bsum, cursor);
    k_scatter   <<<dim3(1563), dim3(256), 0, stream>>>(nidx, cursor, eid);
    fused_main  <<<dim3(NB_TOT), dim3(512), 0, stream>>>(x, rbf, w_rbf, bs, w_out,
                                                         wf, starts, eid, xspe, outp);
}

// Round 6
// 638.906 us; speedup vs baseline: 1.1819x; 1.1819x over previous
//
#include <hip/hip_runtime.h>

#define E_TOT   400000
#define N_NODES 50000
#define NSCAN_BLK 196
#define TWR_BLOCKS 1563      // ceil(400000/256)

typedef _Float16 f16x8 __attribute__((ext_vector_type(8)));
typedef float    f32x2 __attribute__((ext_vector_type(2)));
typedef float    f32x4 __attribute__((ext_vector_type(4)));
typedef float    f32x16 __attribute__((ext_vector_type(16)));
typedef int      i32x4 __attribute__((ext_vector_type(4)));

__device__ __forceinline__ f32x16 zero16() {
    f32x16 z = {0.f,0.f,0.f,0.f,0.f,0.f,0.f,0.f,0.f,0.f,0.f,0.f,0.f,0.f,0.f,0.f};
    return z;
}

__device__ __forceinline__ void gld_lds16(const _Float16* g, _Float16* l) {
    __builtin_amdgcn_global_load_lds(
        (const __attribute__((address_space(1))) unsigned int*)g,
        (__attribute__((address_space(3))) unsigned int*)l, 16, 0, 0);
}

__device__ __forceinline__ int packh2(float a, float b) {
    unsigned la = __builtin_bit_cast(unsigned short, (_Float16)a);
    unsigned lb = __builtin_bit_cast(unsigned short, (_Float16)b);
    return (int)(la | (lb << 16));
}

// ---------------------------------------------------------------------------
// prep: A-fragment-ordered f16 weights (weights are the MFMA A operand).
// A = W^T [M=d_out][K=d_in]; frag fid = kb*8+mf (kb-major), 512 f16/frag:
//   elem(lane=(l31,h), j) = W[kb*16+8h+j][mf*32+l31]
// Sections: [0,32768) w_up (kb 0..7); then per layer 69632 f16 (kb 0..16,
// kb==16 = bias column frag: value at j==0&&h==0 else 0).
// ---------------------------------------------------------------------------
__global__ void prep_weights(const float* __restrict__ w_up,
                             const float* __restrict__ Ws,
                             const float* __restrict__ bs,
                             _Float16* __restrict__ wf)
{
    int t = blockIdx.x * 256 + threadIdx.x;   // 0..241663 (944 blocks exact)
    int idx  = t & 511;
    int j    = idx & 7;
    int lane = idx >> 3;
    int l31  = lane & 31;
    int h    = lane >> 5;
    int fid  = t >> 9;
    float v;
    if (fid < 64) {
        int kb = fid >> 3, mf = fid & 7;
        v = w_up[(kb*16 + 8*h + j)*256 + mf*32 + l31];
    } else {
        int f2 = fid - 64;
        int layer = f2 / 136;
        int fl = f2 - layer * 136;
        int kb = fl >> 3, mf = fl & 7;
        if (kb < 16)
            v = Ws[layer*65536 + (kb*16 + 8*h + j)*256 + mf*32 + l31];
        else
            v = (j == 0 && h == 0) ? bs[layer*256 + mf*32 + l31] : 0.f;
    }
    wf[t] = (_Float16)v;
}

// ---------------------------------------------------------------------------
// CSR build (proven in R3-R5)
// ---------------------------------------------------------------------------
__global__ void k_hist(const int* __restrict__ ni, int* __restrict__ counts) {
    int e = blockIdx.x * 256 + threadIdx.x;
    if (e < E_TOT) atomicAdd(&counts[ni[e]], 1);
}

__global__ void k_scan_block(const int* __restrict__ counts,
                             int* __restrict__ starts, int* __restrict__ bsum) {
    __shared__ int s[256];
    int tid = threadIdx.x;
    int idx = blockIdx.x * 256 + tid;
    int v = (idx < N_NODES) ? counts[idx] : 0;
    s[tid] = v; __syncthreads();
    #pragma unroll
    for (int off = 1; off < 256; off <<= 1) {
        int t = (tid >= off) ? s[tid - off] : 0; __syncthreads();
        s[tid] += t; __syncthreads();
    }
    if (idx < N_NODES) starts[idx] = s[tid] - v;
    if (tid == 255) bsum[blockIdx.x] = s[255];
}

__global__ void k_scan_top(int* __restrict__ bsum) {
    __shared__ int s[256];
    int tid = threadIdx.x;
    int v = (tid < NSCAN_BLK) ? bsum[tid] : 0;
    s[tid] = v; __syncthreads();
    #pragma unroll
    for (int off = 1; off < 256; off <<= 1) {
        int t = (tid >= off) ? s[tid - off] : 0; __syncthreads();
        s[tid] += t; __syncthreads();
    }
    if (tid < NSCAN_BLK) bsum[tid] = s[tid] - v;
}

__global__ void k_scan_add(int* __restrict__ starts, const int* __restrict__ bsum,
                           int* __restrict__ cursor) {
    int idx = blockIdx.x * 256 + threadIdx.x;
    if (idx < N_NODES) {
        int v = starts[idx] + bsum[blockIdx.x];
        starts[idx] = v;
        cursor[idx] = v;
    }
    if (idx == 0) starts[N_NODES] = E_TOT;
}

__global__ void k_scatter(const int* __restrict__ ni, int* __restrict__ cursor,
                          int* __restrict__ eid) {
    int e = blockIdx.x * 256 + threadIdx.x;
    if (e < E_TOT) {
        int slot = atomicAdd(&cursor[ni[e]], 1);
        eid[slot] = e;
    }
}

// ---------------------------------------------------------------------------
// gather: ONE node per wave (50000 waves), lanes cover 2 cols each.
// ---------------------------------------------------------------------------
__global__ __launch_bounds__(512)
void k_gather(const float* __restrict__ x, const float* __restrict__ rbf,
              const float* __restrict__ w_rbf, const int* __restrict__ starts,
              const int* __restrict__ eid, float* __restrict__ xspe)
{
    int wv = threadIdx.x >> 6, l = threadIdx.x & 63;
    int node = blockIdx.x * 8 + wv;        // 6250*8 = 50000 exact
    int c0 = l * 2;
    float w0[6], w1[6];
    #pragma unroll
    for (int r = 0; r < 6; ++r) { w0[r] = w_rbf[r*128 + c0]; w1[r] = w_rbf[r*128 + c0 + 1]; }
    int kb = starts[node], ke = starts[node + 1];
    float a0 = 0.f, a1 = 0.f;
    for (int k = kb; k < ke; ++k) {
        int ed = eid[k];
        f32x2 xv = *(const f32x2*)(x + (size_t)ed * 128 + c0);
        float s0 = 0.f, s1 = 0.f;
        #pragma unroll
        for (int r = 0; r < 6; ++r) {
            float rv = rbf[(size_t)ed * 6 + r];
            s0 += rv * w0[r]; s1 += rv * w1[r];
        }
        a0 += s0 * xv[0]; a1 += s1 * xv[1];
    }
    f32x2 o = {a0, a1};
    *(f32x2*)(xspe + (size_t)node * 128 + c0) = o;
}

// ---------------------------------------------------------------------------
// tower: per wave, 32 edges; t^T register-resident as MFMA B-fragments.
// D = W^T(A, from LDS dbuf) x t^T(B, regs). C-layout -> next B-frags via
// in-register bit2/bit3 redistribution (shfl_xor 32). Bias = extra K slot.
// ---------------------------------------------------------------------------
// epilogue: acc (C-layout) -> breg (B-frags), optional silu.
// derivation: lane(l31,h) holds d with bit2=h; B-frag needs bit3=h.
// P-q packed pairs (h=0): q0(0,1) q1(2,3) q2(8,9) q3(10,11) q4(16,17)
// q5(18,19) q6(24,25) q7(26,27); h=1: +4. Exchange slots S0..S3 carry
// {P2,P3,P6,P7} from h=0 and {P0,P1,P4,P5} from h=1.
#define EPI(DO_SILU) \
    _Pragma("unroll") \
    for (int mf = 0; mf < 8; ++mf) { \
        float sv[16]; \
        _Pragma("unroll") \
        for (int r = 0; r < 16; ++r) { \
            float v = acc[mf][r]; \
            if (DO_SILU) v = v * __builtin_amdgcn_rcpf(1.0f + __expf(-v)); \
            sv[r] = v; \
        } \
        int P0 = packh2(sv[0],  sv[1]);  int P1 = packh2(sv[2],  sv[3]); \
        int P2 = packh2(sv[4],  sv[5]);  int P3 = packh2(sv[6],  sv[7]); \
        int P4 = packh2(sv[8],  sv[9]);  int P5 = packh2(sv[10], sv[11]); \
        int P6 = packh2(sv[12], sv[13]); int P7 = packh2(sv[14], sv[15]); \
        int S0 = h ? P0 : P2;  int S1 = h ? P1 : P3; \
        int S2 = h ? P4 : P6;  int S3 = h ? P5 : P7; \
        int R0 = __shfl_xor(S0, 32); int R1 = __shfl_xor(S1, 32); \
        int R2 = __shfl_xor(S2, 32); int R3 = __shfl_xor(S3, 32); \
        i32x4 lo, hi2; \
        lo[0]  = h ? R0 : P0;  lo[1]  = h ? R1 : P1; \
        lo[2]  = h ? P2 : R0;  lo[3]  = h ? P3 : R1; \
        hi2[0] = h ? R2 : P4;  hi2[1] = h ? R3 : P5; \
        hi2[2] = h ? P6 : R2;  hi2[3] = h ? P7 : R3; \
        breg[2*mf]     = __builtin_bit_cast(f16x8, lo); \
        breg[2*mf + 1] = __builtin_bit_cast(f16x8, hi2); \
    }

__global__ __launch_bounds__(512, 2)
void k_tower(const float* __restrict__ x, const float* __restrict__ rbf,
             const float* __restrict__ w_rbf, const float* __restrict__ w_out,
             const _Float16* __restrict__ wf, float* __restrict__ out)
{
    __shared__ __align__(16) _Float16 wb0[36864];   // 72 KB (b-chunks, 9 kb)
    __shared__ __align__(16) _Float16 wb1[32768];   // 64 KB (a-chunks, 8 kb)
    __shared__ float lwr[768];                      // w_rbf [6][128]
    __shared__ float lwo[256];                      // w_out

    const int tid = threadIdx.x;
    const int l   = tid & 63;
    const int wv  = tid >> 6;
    const int l31 = l & 31;
    const int h   = l >> 5;
    const int e   = blockIdx.x * 256 + wv * 32 + l31;
    const int eL  = (e < E_TOT) ? e : (E_TOT - 1);

    // issue C0 (w_up) -> wb0 ; stage lwr/lwo
    #pragma unroll
    for (int i = 0; i < 8; ++i)
        gld_lds16(wf + ((i*8 + wv) << 9) + l*8, wb0 + ((i*8 + wv) << 9));
    for (int i = tid; i < 768; i += 512) lwr[i] = w_rbf[i];
    if (tid < 256) lwo[tid] = w_out[tid];
    __syncthreads();                               // (1) C0 + lwr ready

    // ---- stage 1: h as GEMM1 B-fragments, fully in registers ----
    float rb[6];
    {
        f32x2 r01 = *(const f32x2*)(rbf + (size_t)eL*6 + 0);
        f32x2 r23 = *(const f32x2*)(rbf + (size_t)eL*6 + 2);
        f32x2 r45 = *(const f32x2*)(rbf + (size_t)eL*6 + 4);
        rb[0]=r01[0]; rb[1]=r01[1]; rb[2]=r23[0]; rb[3]=r23[1]; rb[4]=r45[0]; rb[5]=r45[1];
    }
    f16x8 breg1[8];
    #pragma unroll
    for (int kb = 0; kb < 8; ++kb) {
        int base = kb*16 + 8*h;
        f32x4 xa = *(const f32x4*)(x + (size_t)eL*128 + base);
        f32x4 xb = *(const f32x4*)(x + (size_t)eL*128 + base + 4);
        f32x4 wa[6], wc[6];
        #pragma unroll
        for (int r = 0; r < 6; ++r) {
            wa[r] = *(const f32x4*)&lwr[r*128 + base];
            wc[r] = *(const f32x4*)&lwr[r*128 + base + 4];
        }
        f16x8 hv;
        #pragma unroll
        for (int j = 0; j < 8; ++j) {
            float s = 0.f;
            #pragma unroll
            for (int r = 0; r < 6; ++r) s += rb[r] * ((j < 4) ? wa[r][j] : wc[r][j-4]);
            float xv = (j < 4) ? xa[j] : xb[j-4];
            hv[j] = (_Float16)(s * xv);
        }
        breg1[kb] = hv;
    }

    // ---- GEMM1: t1 = w_up^T x h^T (K=128, no bias/act) ----
    f32x16 acc[8];
    #pragma unroll
    for (int mf = 0; mf < 8; ++mf) acc[mf] = zero16();
    {   // issue C1 = L0 kb0-7 -> wb1
        const _Float16* src = wf + 32768;
        #pragma unroll
        for (int i = 0; i < 8; ++i)
            gld_lds16(src + ((i*8 + wv) << 9) + l*8, wb1 + ((i*8 + wv) << 9));
    }
    #pragma unroll
    for (int kb = 0; kb < 8; ++kb) {
        #pragma unroll
        for (int mf = 0; mf < 8; ++mf) {
            f16x8 af = *(const f16x8*)&wb0[((kb*8 + mf) << 9) + l*8];
            acc[mf] = __builtin_amdgcn_mfma_f32_32x32x16_f16(af, breg1[kb], acc[mf], 0, 0, 0);
        }
    }
    f16x8 breg[16];
    EPI(0)                                          // no silu on up-projection
    __syncthreads();                                // (2) C1 ready

    // ---- 3 layers: t = silu(W^T t + b) ----
    #pragma unroll 1
    for (int L = 0; L < 3; ++L) {
        const _Float16* lbase = wf + 32768 + L * 69632;
        #pragma unroll
        for (int mf = 0; mf < 8; ++mf) acc[mf] = zero16();
        {   // issue C_b (kb 8..16 incl bias) -> wb0
            const _Float16* src = lbase + 32768;
            #pragma unroll
            for (int i = 0; i < 9; ++i)
                gld_lds16(src + ((i*8 + wv) << 9) + l*8, wb0 + ((i*8 + wv) << 9));
        }
        #pragma unroll
        for (int kb = 0; kb < 8; ++kb) {
            #pragma unroll
            for (int mf = 0; mf < 8; ++mf) {
                f16x8 af = *(const f16x8*)&wb1[((kb*8 + mf) << 9) + l*8];
                acc[mf] = __builtin_amdgcn_mfma_f32_32x32x16_f16(af, breg[kb], acc[mf], 0, 0, 0);
            }
        }
        __syncthreads();                            // C_b ready; wb1 free
        if (L < 2) {                                // issue next layer's a-chunk
            const _Float16* src = wf + 32768 + (L+1) * 69632;
            #pragma unroll
            for (int i = 0; i < 8; ++i)
                gld_lds16(src + ((i*8 + wv) << 9) + l*8, wb1 + ((i*8 + wv) << 9));
        }
        #pragma unroll
        for (int kk = 0; kk < 9; ++kk) {
            f16x8 bf;
            if (kk == 8) {                          // bias slot: B = ones at k==0
                f16x8 bone;
                #pragma unroll
                for (int jj = 0; jj < 8; ++jj) bone[jj] = (_Float16)0.f;
                bone[0] = (h == 0) ? (_Float16)1.f : (_Float16)0.f;
                bf = bone;
            } else bf = breg[8 + kk];
            #pragma unroll
            for (int mf = 0; mf < 8; ++mf) {
                f16x8 af = *(const f16x8*)&wb0[((kk*8 + mf) << 9) + l*8];
                acc[mf] = __builtin_amdgcn_mfma_f32_32x32x16_f16(af, bf, acc[mf], 0, 0, 0);
            }
        }
        EPI(1)                                      // silu + transform
        __syncthreads();                            // next a-chunk ready
    }

    // ---- out = t3 . w_out (O=1), in-register dot ----
    float sum = 0.f;
    #pragma unroll
    for (int kb = 0; kb < 16; ++kb) {
        int base = kb*16 + 8*h;
        f32x4 wa = *(const f32x4*)&lwo[base];
        f32x4 wc = *(const f32x4*)&lwo[base + 4];
        f16x8 t = breg[kb];
        sum += (float)t[0]*wa[0] + (float)t[1]*wa[1] + (float)t[2]*wa[2] + (float)t[3]*wa[3]
             + (float)t[4]*wc[0] + (float)t[5]*wc[1] + (float)t[6]*wc[2] + (float)t[7]*wc[3];
    }
    sum += __shfl_xor(sum, 32);
    if (h == 0 && e < E_TOT) out[e] = sum;
}

extern "C" void kernel_launch(void* const* d_in, const int* in_sizes, int n_in,
                              void* d_out, int out_size, void* d_ws, size_t ws_size,
                              hipStream_t stream)
{
    const float* x     = (const float*)d_in[0];
    const float* rbf   = (const float*)d_in[1];
    const int*   nidx  = (const int*)d_in[2];
    const float* w_rbf = (const float*)d_in[3];
    const float* w_up  = (const float*)d_in[4];
    const float* Ws    = (const float*)d_in[5];
    const float* bs    = (const float*)d_in[6];
    const float* w_out = (const float*)d_in[7];

    float* xspe = (float*)d_out;                       // [N,128]
    float* outp = xspe + (size_t)N_NODES * 128;        // [E,1]

    char* ws = (char*)d_ws;
    _Float16* wf = (_Float16*)ws;                      // 483328 B
    int* counts  = (int*)(ws + 0x080000);
    int* starts  = (int*)(ws + 0x0C0000);
    int* cursor  = (int*)(ws + 0x100000);
    int* bsum    = (int*)(ws + 0x140000);
    int* eid     = (int*)(ws + 0x150000);

    hipMemsetAsync(counts, 0, N_NODES * sizeof(int), stream);
    prep_weights<<<dim3(944),  dim3(256), 0, stream>>>(w_up, Ws, bs, wf);
    k_tower     <<<dim3(TWR_BLOCKS), dim3(512), 0, stream>>>(x, rbf, w_rbf, w_out, wf, outp);
    k_hist      <<<dim3(1563), dim3(256), 0, stream>>>(nidx, counts);
    k_scan_block<<<dim3(NSCAN_BLK), dim3(256), 0, stream>>>(counts, starts, bsum);
    k_scan_top  <<<dim3(1),    dim3(256), 0, stream>>>(bsum);
    k_scan_add  <<<dim3(NSCAN_BLK), dim3(256), 0, stream>>>(starts, bsum, cursor);
    k_scatter   <<<dim3(1563), dim3(256), 0, stream>>>(nidx, cursor, eid);
    k_gather    <<<dim3(6250), dim3(512), 0, stream>>>(x, rbf, w_rbf, starts, eid, xspe);
}